// Round 4
// baseline (984.914 us; speedup 1.0000x reference)
//
#include <hip/hip_runtime.h>

// ---------------------------------------------------------------------------
// DistMultNN (HolE-style scoring) on MI355X.
// out[s] = 3*x^T V x - (Vb).x - 0.25*(b^T V b) - x.x,  x = r * circcorr(e1,e2)
// V = inv(W - I): 1-block look-ahead-pipelined blocked Gauss-Jordan
// (16-wide panels, 16 macro steps, ONE barrier each; panel GJ for step kg+1
// runs in wave kg+1's registers via shfl, overlapped with the rank-16 update
// of step kg on the other 15 waves) + 2 Newton-Schulz polish iterations.
// ---------------------------------------------------------------------------

// ============ Kernel 1: pipelined blocked Gauss-Jordan inverse, 1 block =====
// 1024 threads = 16 waves. Wave w owns rows 16w..16w+15. Within a wave:
// lane = h*32+cg; thread tile = rows (16w+8h..+7) x cols (8cg..+7), 64 VGPRs.
// Macro step kg: waves w!=kg apply the rank-16 update from rowbuf/colbuf[p];
// wave kg+1 then panels its (updated) 16x256 row-block in registers (shfl
// broadcasts, no LDS) and publishes rowbuf[p^1] (+I on the K-cols trick);
// lanes owning cols of K_{kg+1} publish colbuf[p^1]. One barrier per step.
__global__ __launch_bounds__(1024)
__attribute__((amdgpu_waves_per_eu(4, 4)))
void gj_inv_kernel(const float* __restrict__ W, float* __restrict__ V0) {
  const int tid  = threadIdx.x;
  const int w    = tid >> 6;        // wave: rows 16w..16w+15
  const int lane = tid & 63;
  const int h    = lane >> 5;       // half: local rows 8h..8h+7
  const int cg   = lane & 31;       // col group: cols 8cg..8cg+7
  const int r0g  = (w << 4) + (h << 3);  // first global row of my tile
  const int c0   = cg << 3;              // first global col of my tile

  float g[8][8];

  __shared__ float rowbuf[2][16][264];   // [parity][m][col] scaled pivot rows
  __shared__ float colbuf[2][256][16];   // [parity][row][m] pre-update K-cols

  // ---- load A = W - I ----
#pragma unroll
  for (int i = 0; i < 8; ++i) {
    float4 a = *(const float4*)&W[(r0g + i) * 256 + c0];
    float4 b = *(const float4*)&W[(r0g + i) * 256 + c0 + 4];
    g[i][0] = a.x; g[i][1] = a.y; g[i][2] = a.z; g[i][3] = a.w;
    g[i][4] = b.x; g[i][5] = b.y; g[i][6] = b.z; g[i][7] = b.w;
#pragma unroll
    for (int j = 0; j < 8; ++j)
      if ((r0g + i) == (c0 + j)) g[i][j] -= 1.0f;
  }

  // In-register panel GJ over this wave's 16x256 row-block (block index kgp).
  // All register indices compile-time (kj fully unrolled). Leaves
  // [ Pinv (in K-cols) | Pinv*A_rest ] in the tile registers.
  auto panel = [&](int kgp) {
#pragma unroll
    for (int kj = 0; kj < 16; ++kj) {
      const int hk  = kj >> 3;           // half holding pivot row (static)
      const int ik  = kj & 7;            // local row / reg col idx (static)
      const int cgk = 2 * kgp + hk;      // col-group holding pivot col (uniform)
      float c[8];
#pragma unroll
      for (int i = 0; i < 8; ++i)
        c[i] = __shfl(g[i][ik], (lane & 32) + cgk, 64);   // my rows' col-k vals
      const float pv = __shfl(g[ik][ik], (hk << 5) + cgk, 64);
      const float pr = 1.0f / pv;
      float r[8];
#pragma unroll
      for (int j = 0; j < 8; ++j)
        r[j] = __shfl(g[ik][j], (hk << 5) + cg, 64) * pr; // scaled pivot row
      // eliminate (pivot row masked via ce=0)
#pragma unroll
      for (int i = 0; i < 8; ++i) {
        const float ce = (h == hk && i == ik) ? 0.0f : c[i];
#pragma unroll
        for (int j = 0; j < 8; ++j) g[i][j] = fmaf(-ce, r[j], g[i][j]);
      }
      if (h == hk) {                      // store scaled pivot row
#pragma unroll
        for (int j = 0; j < 8; ++j) g[ik][j] = r[j];
      }
      if (cg == cgk) {                    // K-col: Pinv entries
#pragma unroll
        for (int i = 0; i < 8; ++i)
          g[i][ik] = (h == hk && i == ik) ? pr : -c[i] * pr;
      }
    }
  };

  // Publish my tile rows into rowbuf[buf] with +I on the K-cols (identity
  // trick: the uniform rank-16 FMA then yields -C*Pinv in the K columns).
  auto publish_rowbuf = [&](int buf, int kgp) {
    const bool idlane = (cg == 2 * kgp + h);
#pragma unroll
    for (int i = 0; i < 8; ++i) {
      float v[8];
#pragma unroll
      for (int j = 0; j < 8; ++j)
        v[j] = g[i][j] + ((idlane && j == i) ? 1.0f : 0.0f);
      *(float4*)&rowbuf[buf][8 * h + i][c0]     = make_float4(v[0], v[1], v[2], v[3]);
      *(float4*)&rowbuf[buf][8 * h + i][c0 + 4] = make_float4(v[4], v[5], v[6], v[7]);
    }
  };

  // ---- prologue: colbuf[0] (cols 0..15, initial values) + panel 0 ----
  if (cg <= 1) {
#pragma unroll
    for (int i = 0; i < 8; ++i) {
      *(float4*)&colbuf[0][r0g + i][8 * cg]     = make_float4(g[i][0], g[i][1], g[i][2], g[i][3]);
      *(float4*)&colbuf[0][r0g + i][8 * cg + 4] = make_float4(g[i][4], g[i][5], g[i][6], g[i][7]);
    }
  }
  if (w == 0) {
    panel(0);
    publish_rowbuf(0, 0);
  }

  // ---- main loop: one barrier per macro step ----
  for (int kg = 0; kg < 16; ++kg) {
    __syncthreads();
    const int p = kg & 1;
    if (w != kg) {
      // rank-16 update: g -= C * R  (m blocked by 2: b64 f-reads, b128 rm-reads)
#pragma unroll
      for (int mp = 0; mp < 8; ++mp) {
        float2 fi[8];
#pragma unroll
        for (int i = 0; i < 8; ++i)
          fi[i] = *(const float2*)&colbuf[p][r0g + i][2 * mp];
        float ra[8], rb[8];
        {
          float4 t0 = *(const float4*)&rowbuf[p][2 * mp][c0];
          float4 t1 = *(const float4*)&rowbuf[p][2 * mp][c0 + 4];
          ra[0] = t0.x; ra[1] = t0.y; ra[2] = t0.z; ra[3] = t0.w;
          ra[4] = t1.x; ra[5] = t1.y; ra[6] = t1.z; ra[7] = t1.w;
          float4 t2 = *(const float4*)&rowbuf[p][2 * mp + 1][c0];
          float4 t3 = *(const float4*)&rowbuf[p][2 * mp + 1][c0 + 4];
          rb[0] = t2.x; rb[1] = t2.y; rb[2] = t2.z; rb[3] = t2.w;
          rb[4] = t3.x; rb[5] = t3.y; rb[6] = t3.z; rb[7] = t3.w;
        }
#pragma unroll
        for (int i = 0; i < 8; ++i) {
#pragma unroll
          for (int j = 0; j < 8; ++j) {
            g[i][j] = fmaf(-fi[i].x, ra[j], g[i][j]);
            g[i][j] = fmaf(-fi[i].y, rb[j], g[i][j]);
          }
        }
      }
    }
    if (kg < 15) {
      if (w == kg + 1) {            // look-ahead: factor next panel now
        panel(kg + 1);
        publish_rowbuf(p ^ 1, kg + 1);
      }
      const int cb = cg - (2 * kg + 2);  // publish next step's column block
      if (cb == 0 || cb == 1) {
        const int mb = cb * 8;
#pragma unroll
        for (int i = 0; i < 8; ++i) {
          *(float4*)&colbuf[p ^ 1][r0g + i][mb]     = make_float4(g[i][0], g[i][1], g[i][2], g[i][3]);
          *(float4*)&colbuf[p ^ 1][r0g + i][mb + 4] = make_float4(g[i][4], g[i][5], g[i][6], g[i][7]);
        }
      }
    }
  }

  // ---- write V ----
#pragma unroll
  for (int i = 0; i < 8; ++i) {
    *(float4*)&V0[(r0g + i) * 256 + c0]     = make_float4(g[i][0], g[i][1], g[i][2], g[i][3]);
    *(float4*)&V0[(r0g + i) * 256 + c0 + 4] = make_float4(g[i][4], g[i][5], g[i][6], g[i][7]);
  }
}

// ============ Newton-Schulz polish kernels (256^3 f32 GEMMs) ================
// T = (W - I) * Vin.  A-element A[i][k] = W[k*256+i] - (i==k)  (W symmetric).
__global__ __launch_bounds__(64) void ns_mt_kernel(const float* __restrict__ W,
                                                   const float* __restrict__ Vin,
                                                   float* __restrict__ T) {
  const int bi = blockIdx.x >> 3, bj = blockIdx.x & 7;
  const int ti = threadIdx.x >> 3, tj = threadIdx.x & 7;
  const int i0 = bi * 32 + ti * 4, j0 = bj * 32 + tj * 4;
  float acc[4][4] = {};
  for (int k = 0; k < 256; ++k) {
    float4 a4 = *(const float4*)&W[k * 256 + i0];
    float a[4] = {a4.x, a4.y, a4.z, a4.w};
#pragma unroll
    for (int i = 0; i < 4; ++i) a[i] -= ((i0 + i) == k) ? 1.0f : 0.0f;
    float4 b4 = *(const float4*)&Vin[k * 256 + j0];
    const float b[4] = {b4.x, b4.y, b4.z, b4.w};
#pragma unroll
    for (int i = 0; i < 4; ++i)
#pragma unroll
      for (int j = 0; j < 4; ++j) acc[i][j] += a[i] * b[j];
  }
#pragma unroll
  for (int i = 0; i < 4; ++i) {
    float4 t = make_float4(acc[i][0], acc[i][1], acc[i][2], acc[i][3]);
    *(float4*)&T[(i0 + i) * 256 + j0] = t;
  }
}

// Vout = 2*Vin - Vin*T
__global__ __launch_bounds__(64) void ns_upd_kernel(const float* __restrict__ Vin,
                                                    const float* __restrict__ T,
                                                    float* __restrict__ Vout) {
  const int bi = blockIdx.x >> 3, bj = blockIdx.x & 7;
  const int ti = threadIdx.x >> 3, tj = threadIdx.x & 7;
  const int i0 = bi * 32 + ti * 4, j0 = bj * 32 + tj * 4;
  float acc[4][4] = {};
  for (int k = 0; k < 256; ++k) {
    float a[4];
#pragma unroll
    for (int i = 0; i < 4; ++i) a[i] = Vin[(i0 + i) * 256 + k];
    float4 b4 = *(const float4*)&T[k * 256 + j0];
    const float b[4] = {b4.x, b4.y, b4.z, b4.w};
#pragma unroll
    for (int i = 0; i < 4; ++i)
#pragma unroll
      for (int j = 0; j < 4; ++j) acc[i][j] += a[i] * b[j];
  }
#pragma unroll
  for (int i = 0; i < 4; ++i) {
    float4 v = *(const float4*)&Vin[(i0 + i) * 256 + j0];
    float4 t = make_float4(2.0f * v.x - acc[i][0], 2.0f * v.y - acc[i][1],
                           2.0f * v.z - acc[i][2], 2.0f * v.w - acc[i][3]);
    *(float4*)&Vout[(i0 + i) * 256 + j0] = t;
  }
}

// ============ u = V*b, c0 = b.u ==============================================
__global__ __launch_bounds__(256) void compute_u_kernel(const float* __restrict__ V,
                                                        const float* __restrict__ b,
                                                        float* __restrict__ u,
                                                        float* __restrict__ c0) {
  const int tid = threadIdx.x;
  __shared__ float bs[256];
  __shared__ float us[256];
  bs[tid] = b[tid];
  __syncthreads();
  float acc = 0.0f;
  for (int j = 0; j < 256; j += 4) {
    float4 v4 = *(const float4*)&V[tid * 256 + j];
    acc += v4.x * bs[j] + v4.y * bs[j + 1] + v4.z * bs[j + 2] + v4.w * bs[j + 3];
  }
  u[tid] = acc;
  us[tid] = acc * bs[tid];
  __syncthreads();
  if (tid < 64) {
    float s = us[tid] + us[tid + 64] + us[tid + 128] + us[tid + 192];
#pragma unroll
    for (int off = 32; off > 0; off >>= 1) s += __shfl_down(s, off);
    if (tid == 0) c0[0] = s;
  }
}

// ============ Main fused kernel: cc + x + x^T V x + epilogue =================
// 2048 blocks x 256 threads; 32 samples/block (2 cc rounds of 16).
__global__ __launch_bounds__(256) void main_kernel(
    const float* __restrict__ E_ent, const float* __restrict__ E_rel,
    const int* __restrict__ samples, const float* __restrict__ V,
    const float* __restrict__ u, const float* __restrict__ c0p,
    float* __restrict__ out) {
  const int tid = threadIdx.x;
  const int sbase = blockIdx.x * 32;

  __shared__ float e1buf[16][268];   // stride 268: 16B-aligned rows, banks spread
  __shared__ float e2buf[16][268];
  __shared__ float xbuf[256][32];    // x transposed: [k][sample]
  __shared__ float ubuf[256];

  ubuf[tid] = u[tid];

  for (int rnd = 0; rnd < 2; ++rnd) {
    __syncthreads();  // protect e1/e2 reuse across rounds; ubuf visibility
    {  // stage 16 samples' e1,e2 rows (coalesced: 16 lanes span one 1KB row)
      const int ss = tid >> 4;
      const int f0 = (tid & 15) << 4;
      const int sg = sbase + rnd * 16 + ss;
      const int ie1 = samples[sg * 3 + 0];
      const int ie2 = samples[sg * 3 + 2];
      const float* p1 = E_ent + (size_t)ie1 * 256 + f0;
      const float* p2 = E_ent + (size_t)ie2 * 256 + f0;
#pragma unroll
      for (int t = 0; t < 16; t += 4) {
        *(float4*)&e1buf[ss][f0 + t] = *(const float4*)&p1[t];
        *(float4*)&e2buf[ss][f0 + t] = *(const float4*)&p2[t];
      }
    }
    __syncthreads();
    {  // cc: thread (l=tid>>4 -> k-tile of 16, g=tid&15 -> sample)
      const int l = tid >> 4;
      const int g = tid & 15;
      const int k0 = l << 4;
      float acc[16] = {};
      for (int j0 = 0; j0 < 256; j0 += 16) {
        float e1c[16], ea[16], eb[16];
#pragma unroll
        for (int t = 0; t < 16; t += 4) {
          float4 v = *(const float4*)&e1buf[g][j0 + t];
          e1c[t] = v.x; e1c[t + 1] = v.y; e1c[t + 2] = v.z; e1c[t + 3] = v.w;
        }
        const int h0 = (j0 + k0) & 255;
        const int h1 = (h0 + 16) & 255;
#pragma unroll
        for (int t = 0; t < 16; t += 4) {
          float4 va = *(const float4*)&e2buf[g][h0 + t];
          ea[t] = va.x; ea[t + 1] = va.y; ea[t + 2] = va.z; ea[t + 3] = va.w;
          float4 vb = *(const float4*)&e2buf[g][h1 + t];
          eb[t] = vb.x; eb[t + 1] = vb.y; eb[t + 2] = vb.z; eb[t + 3] = vb.w;
        }
#pragma unroll
        for (int jj = 0; jj < 16; ++jj)
#pragma unroll
          for (int m = 0; m < 16; ++m) {
            const int t = jj + m;
            const float w = (t < 16) ? ea[t] : eb[t - 16];
            acc[m] += e1c[jj] * w;
          }
      }
      // x = r * cc -> xbuf (transposed)
      const int sg = sbase + rnd * 16 + g;
      const int ir = samples[sg * 3 + 1];
      const float* rp = E_rel + (size_t)ir * 256 + k0;
#pragma unroll
      for (int m = 0; m < 16; m += 4) {
        float4 r4 = *(const float4*)&rp[m];
        xbuf[k0 + m + 0][rnd * 16 + g] = r4.x * acc[m + 0];
        xbuf[k0 + m + 1][rnd * 16 + g] = r4.y * acc[m + 1];
        xbuf[k0 + m + 2][rnd * 16 + g] = r4.z * acc[m + 2];
        xbuf[k0 + m + 3][rnd * 16 + g] = r4.w * acc[m + 3];
      }
    }
  }
  __syncthreads();

  // GEMM phase: ts=tid>>5 -> 4 samples; tc=tid&31 -> 8 V-columns
  const int ts = tid >> 5, tc = tid & 31;
  const int s0 = ts << 2;
  const int cc0 = tc << 3;
  float z[4][8] = {};
#pragma unroll 4
  for (int l = 0; l < 256; ++l) {
    float4 xv = *(const float4*)&xbuf[l][s0];
    const float xa[4] = {xv.x, xv.y, xv.z, xv.w};
    float4 v0 = *(const float4*)&V[l * 256 + cc0];
    float4 v1 = *(const float4*)&V[l * 256 + cc0 + 4];
    const float vv[8] = {v0.x, v0.y, v0.z, v0.w, v1.x, v1.y, v1.z, v1.w};
#pragma unroll
    for (int i = 0; i < 4; ++i)
#pragma unroll
      for (int j = 0; j < 8; ++j) z[i][j] += xa[i] * vv[j];
  }
  // epilogue: dp = sum_c z*x ; dxx = sum_c x^2 ; dux = sum_c u*x  (per sample)
  float dp[4] = {}, dxx[4] = {}, dux[4] = {};
#pragma unroll
  for (int j = 0; j < 8; ++j) {
    float4 xv = *(const float4*)&xbuf[cc0 + j][s0];
    const float xa[4] = {xv.x, xv.y, xv.z, xv.w};
    const float uu = ubuf[cc0 + j];
#pragma unroll
    for (int i = 0; i < 4; ++i) {
      dp[i]  += z[i][j] * xa[i];
      dxx[i] += xa[i] * xa[i];
      dux[i] += uu * xa[i];
    }
  }
#pragma unroll
  for (int off = 1; off < 32; off <<= 1) {
#pragma unroll
    for (int i = 0; i < 4; ++i) {
      dp[i]  += __shfl_xor(dp[i], off);
      dxx[i] += __shfl_xor(dxx[i], off);
      dux[i] += __shfl_xor(dux[i], off);
    }
  }
  if (tc == 0) {
    const float c0v = c0p[0];
#pragma unroll
    for (int i = 0; i < 4; ++i) {
      out[sbase + s0 + i] = 3.0f * dp[i] - dux[i] - 0.25f * c0v - dxx[i];
    }
  }
}

// ============================ launcher ======================================
extern "C" void kernel_launch(void* const* d_in, const int* in_sizes, int n_in,
                              void* d_out, int out_size, void* d_ws, size_t ws_size,
                              hipStream_t stream) {
  const float* E_ent   = (const float*)d_in[0];
  const float* E_rel   = (const float*)d_in[1];
  const float* W       = (const float*)d_in[2];
  const float* b       = (const float*)d_in[3];
  const int*   samples = (const int*)d_in[4];
  float* out = (float*)d_out;
  float* ws  = (float*)d_ws;

  float* VA = ws;            // 65536 f32 (V0 -> final V)
  float* VB = ws + 65536;    // T scratch
  float* VC = ws + 131072;   // V1
  float* ub = ws + 196608;   // 256
  float* c0 = ws + 196864;   // 1

  gj_inv_kernel<<<1, 1024, 0, stream>>>(W, VA);
  // Newton-Schulz polish x2: V <- V(2I - (W-I)V)
  ns_mt_kernel<<<64, 64, 0, stream>>>(W, VA, VB);
  ns_upd_kernel<<<64, 64, 0, stream>>>(VA, VB, VC);
  ns_mt_kernel<<<64, 64, 0, stream>>>(W, VC, VB);
  ns_upd_kernel<<<64, 64, 0, stream>>>(VC, VB, VA);
  compute_u_kernel<<<1, 256, 0, stream>>>(VA, b, ub, c0);

  main_kernel<<<65536 / 32, 256, 0, stream>>>(E_ent, E_rel, samples, VA, ub, c0, out);
}

// Round 5
// 588.004 us; speedup vs baseline: 1.6750x; 1.6750x over previous
//
#include <hip/hip_runtime.h>
#include <hip/hip_fp16.h>
#include <hip/hip_cooperative_groups.h>

namespace cg = cooperative_groups;

// ---------------------------------------------------------------------------
// DistMultNN fused cooperative kernel (MI355X).
// out[s] = 3*x^T V x - (Vb).x - 0.25*(b^T V b) - x.x,  x = r * circcorr(e1,e2)
// One cooperative launch, 256 blocks x 1024 threads (all co-resident):
//   phase1: block 0 = Gauss-Jordan inverse (measured round-3 code);
//           blocks 1..255 = cc+x for ALL samples, x kept packed-f16 in regs.
//   grid.sync -> Newton-Schulz polish x2 (grid-wide, LDS-staged) -> u,c0
//   -> per-block GEMM (x^T V x) with V staged in LDS chunks -> out.
// ---------------------------------------------------------------------------

#define ERS 268      // e1/e2 LDS row stride (floats)
#define VTS 264      // V tile LDS row stride (floats)
#define REGION_F 18432

__global__ __launch_bounds__(1024, 4)
void fused_kernel(const float* __restrict__ E_ent, const float* __restrict__ E_rel,
                  const float* __restrict__ W, const float* __restrict__ bvec,
                  const int* __restrict__ samples, float* __restrict__ out,
                  float* __restrict__ VA, float* __restrict__ VB, float* __restrict__ VC,
                  float* __restrict__ ub, float* __restrict__ c0g) {
  __shared__ float regionY[REGION_F];     // 72 KB, phase-unioned
  __shared__ __half xbuf[4][256][32];     // 64 KB: x transposed per quarter-batch
  __shared__ float ubuf[256];

  const int tid = threadIdx.x;
  const int blk = blockIdx.x;
  cg::grid_group grid = cg::this_grid();

  __half2 x_reg[9][4];                    // packed x, 9 batches x 8 k-values
#pragma unroll
  for (int t = 0; t < 9; ++t)
#pragma unroll
    for (int p = 0; p < 4; ++p) x_reg[t][p] = __floats2half2_rn(0.f, 0.f);

  const bool has9 = (blk >= 248);

  // =================== phase 1: GJ (block 0) || cc (blocks 1..255) =========
  if (blk == 0) {
    // ---- blocked in-place Gauss-Jordan (round-3 code, LDS carved) ----
    const int tx = tid & 31, ty = tid >> 5;
    const int r0 = ty << 3, gc0 = tx << 3;
    float (*rowbuf)[264] = (float(*)[264])&regionY[0];        // 8 x 264
    float (*colbuf)[8]   = (float(*)[8])&regionY[8 * 264];    // 256 x 8
    float gg[8][8];
#pragma unroll
    for (int i = 0; i < 8; ++i) {
      const float4 wa = *(const float4*)&W[(r0 + i) * 256 + gc0];
      const float4 wb = *(const float4*)&W[(r0 + i) * 256 + gc0 + 4];
      gg[i][0] = wa.x; gg[i][1] = wa.y; gg[i][2] = wa.z; gg[i][3] = wa.w;
      gg[i][4] = wb.x; gg[i][5] = wb.y; gg[i][6] = wb.z; gg[i][7] = wb.w;
#pragma unroll
      for (int j = 0; j < 8; ++j)
        if ((r0 + i) == (gc0 + j)) gg[i][j] -= 1.0f;
    }
    __syncthreads();
    for (int kg = 0; kg < 32; ++kg) {
      if (ty == kg) {
        const int L0 = (kg & 1) << 5;
#pragma unroll
        for (int kj = 0; kj < 8; ++kj) {
          float c[8];
#pragma unroll
          for (int i = 0; i < 8; ++i) c[i] = __shfl(gg[i][kj], L0 + kg, 64);
          const float pr = 1.0f / c[kj];
#pragma unroll
          for (int j = 0; j < 8; ++j) gg[kj][j] *= pr;
          if (tx == kg) gg[kj][kj] = pr;
#pragma unroll
          for (int i = 0; i < 8; ++i) {
            if (i == kj) continue;
#pragma unroll
            for (int j = 0; j < 8; ++j) gg[i][j] = fmaf(-c[i], gg[kj][j], gg[i][j]);
            if (tx == kg) gg[i][kj] = -c[i] * pr;
          }
        }
#pragma unroll
        for (int m = 0; m < 8; ++m) {
          float r4[8];
#pragma unroll
          for (int j = 0; j < 8; ++j)
            r4[j] = gg[m][j] + ((tx == kg && j == m) ? 1.0f : 0.0f);
          *(float4*)&rowbuf[m][gc0]     = make_float4(r4[0], r4[1], r4[2], r4[3]);
          *(float4*)&rowbuf[m][gc0 + 4] = make_float4(r4[4], r4[5], r4[6], r4[7]);
        }
      } else if (tx == kg) {
#pragma unroll
        for (int i = 0; i < 8; ++i) {
          *(float4*)&colbuf[r0 + i][0] = make_float4(gg[i][0], gg[i][1], gg[i][2], gg[i][3]);
          *(float4*)&colbuf[r0 + i][4] = make_float4(gg[i][4], gg[i][5], gg[i][6], gg[i][7]);
        }
      }
      __syncthreads();
      if (ty != kg) {
#pragma unroll
        for (int m = 0; m < 8; ++m) {
          float rm[8];
          const float4 t0 = *(const float4*)&rowbuf[m][gc0];
          const float4 t1 = *(const float4*)&rowbuf[m][gc0 + 4];
          rm[0] = t0.x; rm[1] = t0.y; rm[2] = t0.z; rm[3] = t0.w;
          rm[4] = t1.x; rm[5] = t1.y; rm[6] = t1.z; rm[7] = t1.w;
#pragma unroll
          for (int i = 0; i < 8; ++i) {
            const float f = colbuf[r0 + i][m];
#pragma unroll
            for (int j = 0; j < 8; ++j) gg[i][j] = fmaf(-f, rm[j], gg[i][j]);
          }
        }
      }
      __syncthreads();
    }
#pragma unroll
    for (int i = 0; i < 8; ++i) {
      *(float4*)&VA[(r0 + i) * 256 + gc0]     = make_float4(gg[i][0], gg[i][1], gg[i][2], gg[i][3]);
      *(float4*)&VA[(r0 + i) * 256 + gc0 + 4] = make_float4(gg[i][4], gg[i][5], gg[i][6], gg[i][7]);
    }
  } else {
    // ---- cc + x for up to 9 batches of 32 samples, pack f16 into regs ----
    float (*e1buf)[ERS] = (float(*)[ERS])&regionY[0];
    float (*e2buf)[ERS] = (float(*)[ERS])&regionY[32 * ERS];
    const int g = tid & 31, l5 = tid >> 5, k0 = l5 << 3;
    const int ss = tid >> 5, f0 = (tid & 31) << 3;
#pragma unroll
    for (int t = 0; t < 9; ++t) {
      const int gb = (t < 8) ? ((blk - 1) * 8 + t) : (2040 + (blk & 7));
      const int sb = gb << 5;
      __syncthreads();
      {
        const int ie1 = samples[(sb + ss) * 3 + 0];
        const int ie2 = samples[(sb + ss) * 3 + 2];
        const float* p1 = E_ent + (size_t)ie1 * 256 + f0;
        const float* p2 = E_ent + (size_t)ie2 * 256 + f0;
        *(float4*)&e1buf[ss][f0]     = *(const float4*)&p1[0];
        *(float4*)&e1buf[ss][f0 + 4] = *(const float4*)&p1[4];
        *(float4*)&e2buf[ss][f0]     = *(const float4*)&p2[0];
        *(float4*)&e2buf[ss][f0 + 4] = *(const float4*)&p2[4];
      }
      __syncthreads();
      float acc[8] = {};
#pragma unroll 2
      for (int j0 = 0; j0 < 256; j0 += 8) {
        float e1v[8], ew[16];
        {
          const float4 a = *(const float4*)&e1buf[g][j0];
          const float4 b = *(const float4*)&e1buf[g][j0 + 4];
          e1v[0] = a.x; e1v[1] = a.y; e1v[2] = a.z; e1v[3] = a.w;
          e1v[4] = b.x; e1v[5] = b.y; e1v[6] = b.z; e1v[7] = b.w;
        }
        const int h0 = (j0 + k0) & 255;
        const int h1 = (h0 + 8) & 255;
        {
          const float4 a = *(const float4*)&e2buf[g][h0];
          const float4 b = *(const float4*)&e2buf[g][h0 + 4];
          const float4 c = *(const float4*)&e2buf[g][h1];
          const float4 d = *(const float4*)&e2buf[g][h1 + 4];
          ew[0] = a.x;  ew[1] = a.y;  ew[2] = a.z;  ew[3] = a.w;
          ew[4] = b.x;  ew[5] = b.y;  ew[6] = b.z;  ew[7] = b.w;
          ew[8] = c.x;  ew[9] = c.y;  ew[10] = c.z; ew[11] = c.w;
          ew[12] = d.x; ew[13] = d.y; ew[14] = d.z; ew[15] = d.w;
        }
#pragma unroll
        for (int m = 0; m < 8; ++m)
#pragma unroll
          for (int jj = 0; jj < 8; ++jj)
            acc[m] = fmaf(e1v[jj], ew[jj + m], acc[m]);
      }
      const int ir = samples[(sb + g) * 3 + 1];
      const float* rp = E_rel + (size_t)ir * 256 + k0;
      const float4 r0v = *(const float4*)&rp[0];
      const float4 r1v = *(const float4*)&rp[4];
      x_reg[t][0] = __floats2half2_rn(r0v.x * acc[0], r0v.y * acc[1]);
      x_reg[t][1] = __floats2half2_rn(r0v.z * acc[2], r0v.w * acc[3]);
      x_reg[t][2] = __floats2half2_rn(r1v.x * acc[4], r1v.y * acc[5]);
      x_reg[t][3] = __floats2half2_rn(r1v.z * acc[6], r1v.w * acc[7]);
    }
  }
  grid.sync();

  // =================== Newton-Schulz polish x2 (blocks 0..63) ==============
  // mt: T = (W-I)*Vin ; upd: Vout = 2*Vin - Vin*T     (LDS-staged tiles)
#pragma unroll 1
  for (int it = 0; it < 2; ++it) {
    const float* Vin = (it == 0) ? VA : VC;
    float* Vout      = (it == 0) ? VC : VA;
    if (blk < 64) {  // mt
      float (*Wt)[36]  = (float(*)[36])&regionY[0];          // 256 x 36
      float (*Vt2)[36] = (float(*)[36])&regionY[256 * 36 / 2 * 0 + 9216];
      const int cbW = (blk >> 3) << 5, cbV = (blk & 7) << 5;
      const int kr = tid >> 2, c8 = (tid & 3) << 3;
      *(float4*)&Wt[kr][c8]      = *(const float4*)&W[kr * 256 + cbW + c8];
      *(float4*)&Wt[kr][c8 + 4]  = *(const float4*)&W[kr * 256 + cbW + c8 + 4];
      *(float4*)&Vt2[kr][c8]     = *(const float4*)&Vin[kr * 256 + cbV + c8];
      *(float4*)&Vt2[kr][c8 + 4] = *(const float4*)&Vin[kr * 256 + cbV + c8 + 4];
      __syncthreads();
      const int i = tid >> 5, j = tid & 31;
      const int gi = cbW + i, gj = cbV + j;
      float acc = 0.f;
#pragma unroll 4
      for (int k = 0; k < 256; ++k)
        acc = fmaf(Wt[k][i] - ((k == gi) ? 1.0f : 0.0f), Vt2[k][j], acc);
      VB[gi * 256 + gj] = acc;
    }
    grid.sync();
    if (blk < 64) {  // upd
      float (*Vr)[264] = (float(*)[264])&regionY[0];         // 32 x 264
      float (*Tt)[36]  = (float(*)[36])&regionY[32 * 264];   // 256 x 36
      const int rb = (blk >> 3) << 5, cb = (blk & 7) << 5;
      const int r32 = tid >> 5, cc8 = (tid & 31) << 3;
      *(float4*)&Vr[r32][cc8]     = *(const float4*)&Vin[(rb + r32) * 256 + cc8];
      *(float4*)&Vr[r32][cc8 + 4] = *(const float4*)&Vin[(rb + r32) * 256 + cc8 + 4];
      const int kr = tid >> 2, c8 = (tid & 3) << 3;
      *(float4*)&Tt[kr][c8]     = *(const float4*)&VB[kr * 256 + cb + c8];
      *(float4*)&Tt[kr][c8 + 4] = *(const float4*)&VB[kr * 256 + cb + c8 + 4];
      __syncthreads();
      const int i = tid >> 5, j = tid & 31;
      float acc = 0.f;
#pragma unroll 4
      for (int k = 0; k < 256; ++k)
        acc = fmaf(Vr[i][k], Tt[k][j], acc);
      Vout[(rb + i) * 256 + cb + j] = 2.0f * Vr[i][cb + j] - acc;
    }
    grid.sync();
  }

  // =================== u = V*b, c0 = b.u (block 0) =========================
  if (blk == 0) {
    float* bs = &regionY[0];
    float* us = &regionY[256];
    if (tid < 256) bs[tid] = bvec[tid];
    __syncthreads();
    if (tid < 256) {
      float uacc = 0.f;
      for (int jj = 0; jj < 256; jj += 4) {
        const float4 v4 = *(const float4*)&VA[tid * 256 + jj];
        uacc += v4.x * bs[jj] + v4.y * bs[jj + 1] + v4.z * bs[jj + 2] + v4.w * bs[jj + 3];
      }
      ub[tid] = uacc;
      us[tid] = uacc * bs[tid];
    }
    __syncthreads();
    if (tid < 64) {
      float s = us[tid] + us[tid + 64] + us[tid + 128] + us[tid + 192];
#pragma unroll
      for (int off = 32; off > 0; off >>= 1) s += __shfl_down(s, off);
      if (tid == 0) c0g[0] = s;
    }
  }
  grid.sync();

  // =================== GEMM phase: z = x^T V, dots, out ====================
  {
    float (*Vt)[VTS] = (float(*)[VTS])&regionY[0];           // 64 x 264
    const int g = tid & 31, l5 = tid >> 5, k0 = l5 << 3;     // unpack mapping
    const int q = tid >> 8, local = tid & 255;               // quarter mapping
    const int s0 = (local >> 5) << 2, tc = local & 31, c0 = tc << 3;
    if (tid < 256) ubuf[tid] = ub[tid];
    const float c0v = c0g[0];

#pragma unroll
    for (int gr = 0; gr < 3; ++gr) {
      // unpack this group's batches into xbuf (f16, transposed [k][sample])
#pragma unroll
      for (int tq = 0; tq < 4; ++tq) {
        if (gr == 2 && tq > 0) continue;
        const int t = (gr < 2) ? (gr * 4 + tq) : 8;
#pragma unroll
        for (int p = 0; p < 4; ++p) {
          const __half2 hv = x_reg[t][p];
          xbuf[tq][k0 + 2 * p][g]     = __low2half(hv);
          xbuf[tq][k0 + 2 * p + 1][g] = __high2half(hv);
        }
      }
      const bool active = (blk != 0) && ((gr < 2) || (has9 && q == 0));
      float z[4][8] = {};
      for (int ch = 0; ch < 4; ++ch) {
        __syncthreads();   // xbuf/Vt producers done before restage
        {
          const int rr = tid >> 4, c16 = (tid & 15) << 4;
          const float* src = VA + (size_t)(ch * 64 + rr) * 256 + c16;
#pragma unroll
          for (int p = 0; p < 16; p += 4)
            *(float4*)&Vt[rr][c16 + p] = *(const float4*)&src[p];
        }
        __syncthreads();
        if (active) {
#pragma unroll 2
          for (int ll = 0; ll < 64; ++ll) {
            const int l = (ch << 6) + ll;
            const __half2 a01 = *(const __half2*)&xbuf[q][l][s0];
            const __half2 a23 = *(const __half2*)&xbuf[q][l][s0 + 2];
            const float xa[4] = {__half2float(__low2half(a01)), __half2float(__high2half(a01)),
                                 __half2float(__low2half(a23)), __half2float(__high2half(a23))};
            const float4 v0 = *(const float4*)&Vt[ll][c0];
            const float4 v1 = *(const float4*)&Vt[ll][c0 + 4];
            const float vv[8] = {v0.x, v0.y, v0.z, v0.w, v1.x, v1.y, v1.z, v1.w};
#pragma unroll
            for (int i = 0; i < 4; ++i)
#pragma unroll
              for (int j = 0; j < 8; ++j) z[i][j] = fmaf(xa[i], vv[j], z[i][j]);
          }
        }
      }
      if (active) {
        float dp[4] = {}, dxx[4] = {}, dux[4] = {};
#pragma unroll
        for (int j = 0; j < 8; ++j) {
          const __half2 a01 = *(const __half2*)&xbuf[q][c0 + j][s0];
          const __half2 a23 = *(const __half2*)&xbuf[q][c0 + j][s0 + 2];
          const float xa[4] = {__half2float(__low2half(a01)), __half2float(__high2half(a01)),
                               __half2float(__low2half(a23)), __half2float(__high2half(a23))};
          const float uu = ubuf[c0 + j];
#pragma unroll
          for (int i = 0; i < 4; ++i) {
            dp[i]  = fmaf(z[i][j], xa[i], dp[i]);
            dxx[i] = fmaf(xa[i], xa[i], dxx[i]);
            dux[i] = fmaf(uu, xa[i], dux[i]);
          }
        }
#pragma unroll
        for (int off = 1; off < 32; off <<= 1)
#pragma unroll
          for (int i = 0; i < 4; ++i) {
            dp[i]  += __shfl_xor(dp[i], off);
            dxx[i] += __shfl_xor(dxx[i], off);
            dux[i] += __shfl_xor(dux[i], off);
          }
        if (tc == 0) {
          const int gb = (gr < 2) ? ((blk - 1) * 8 + gr * 4 + q) : (2040 + (blk & 7));
#pragma unroll
          for (int i = 0; i < 4; ++i)
            out[gb * 32 + s0 + i] = 3.0f * dp[i] - dux[i] - 0.25f * c0v - dxx[i];
        }
      }
      __syncthreads();   // xbuf reads done before next group's unpack
    }
  }
}

// ============================ launcher ======================================
extern "C" void kernel_launch(void* const* d_in, const int* in_sizes, int n_in,
                              void* d_out, int out_size, void* d_ws, size_t ws_size,
                              hipStream_t stream) {
  const float* E_ent   = (const float*)d_in[0];
  const float* E_rel   = (const float*)d_in[1];
  const float* W       = (const float*)d_in[2];
  const float* bvec    = (const float*)d_in[3];
  const int*   samples = (const int*)d_in[4];
  float* out = (float*)d_out;
  float* ws  = (float*)d_ws;

  float* VA = ws;            // 65536 f32 (final V)
  float* VB = ws + 65536;    // NS scratch T
  float* VC = ws + 131072;   // NS intermediate
  float* ub = ws + 196608;   // 256
  float* c0 = ws + 196864;   // 1

  void* args[] = {(void*)&E_ent, (void*)&E_rel, (void*)&W, (void*)&bvec,
                  (void*)&samples, (void*)&out, (void*)&VA, (void*)&VB,
                  (void*)&VC, (void*)&ub, (void*)&c0};
  hipLaunchCooperativeKernel((void*)fused_kernel, dim3(256), dim3(1024),
                             args, 0, stream);
}